// Round 9
// baseline (269.576 us; speedup 1.0000x reference)
//
#include <hip/hip_runtime.h>

#define NNODES 100000
#define NEDGES 1600000
#define KBUCK 196          // ceil(N / 512)
#define RNG 512            // nodes per bucket (dst >> 9)
#define BCAP 9216          // bucket capacity: mean 8192, sd ~90 -> 11 sigma headroom
#define CHUNK 4096         // edges per workgroup in binning pass
#define NBAGG 2048         // aggregate grid (8192 waves -> 8 waves/SIMD)
#define NRED 128           // stage-1 reduction blocks for pblk

typedef __attribute__((ext_vector_type(8))) short bf16x8_t;   // 8 bf16 (4 VGPR)
typedef __attribute__((ext_vector_type(4))) float f32x4_t;    // MFMA acc
typedef __attribute__((ext_vector_type(2))) float f32x2_t;    // packed-f32 pair (v_pk_add_f32)

// ---- bf16 helpers (RNE) ----
__device__ inline unsigned short f2bf(float f) {
    union { float f; unsigned u; } a; a.f = f;
    unsigned r = (a.u + 0x7FFFu + ((a.u >> 16) & 1u)) >> 16;
    return (unsigned short)r;
}
__device__ inline float bfbits_lo(unsigned u) {
    union { unsigned u; float f; } a; a.u = u << 16; return a.f;
}
__device__ inline float bfbits_hi(unsigned u) {
    union { unsigned u; float f; } a; a.u = u & 0xFFFF0000u; return a.f;
}

// unpack uint2 (4 bf16) and add into two f32 pairs (compiler may emit v_pk_add_f32)
__device__ inline void addpk2(f32x2_t& a01, f32x2_t& a23, uint2 v) {
    f32x2_t d0, d1;
    d0.x = bfbits_lo(v.x); d0.y = bfbits_hi(v.x);
    d1.x = bfbits_lo(v.y); d1.y = bfbits_hi(v.y);
    a01 += d0; a23 += d1;
}

// ---------------- pass A: bin edges by dst>>9 into KBUCK buckets (LDS-staged) ----------------
__global__ __launch_bounds__(256) void k_bin(
    const int* __restrict__ src, const int* __restrict__ dst,
    unsigned int* __restrict__ gbuf, int* __restrict__ gcount, int e)
{
    __shared__ unsigned int bins[KBUCK][64];
    __shared__ int bcount[KBUCK];
    const int tid = threadIdx.x;
    for (int i = tid; i < KBUCK; i += 256) bcount[i] = 0;
    __syncthreads();

    int base = blockIdx.x * CHUNK;
    int lim = min(e, base + CHUNK);
    for (int i = base + tid; i < lim; i += 256) {
        int d = dst[i];
        int s = src[i];
        int b = d >> 9;
        unsigned int entry = ((unsigned int)(d & 511) << 17) | (unsigned int)s;
        int idx = atomicAdd(&bcount[b], 1);
        if (idx < 64) {
            bins[b][idx] = entry;
        } else {
            int gpos = atomicAdd(&gcount[b], 1);
            if (gpos < BCAP) gbuf[(size_t)b * BCAP + gpos] = entry;
        }
    }
    __syncthreads();

    for (int b = tid; b < KBUCK; b += 256) {
        int n = min(bcount[b], 64);
        if (n > 0) {
            int pos = atomicAdd(&gcount[b], n);
            int m = min(n, BCAP - pos);
            for (int i = 0; i < m; ++i)
                gbuf[(size_t)b * BCAP + pos + i] = bins[b][i];
        }
    }
}

// ---------------- pass B: per-bucket degree histogram -> deg + dinv ----------------
__global__ __launch_bounds__(256) void k_hist_dinv(
    const unsigned int* __restrict__ gbuf, const int* __restrict__ gcount,
    int* __restrict__ deg, float* __restrict__ dinv, int n)
{
    __shared__ int hist[RNG];
    const int b = blockIdx.x, tid = threadIdx.x;
    for (int i = tid; i < RNG; i += 256) hist[i] = 0;
    __syncthreads();
    int cnt = gcount[b];
    const unsigned int* buf = gbuf + (size_t)b * BCAP;
    for (int j = tid; j < cnt; j += 256)
        atomicAdd(&hist[buf[j] >> 17], 1);
    __syncthreads();
    int nbase = b * RNG;
    for (int i = tid; i < RNG; i += 256) {
        int node = nbase + i;
        if (node < n) {
            int dgi = hist[i];
            deg[node] = dgi;
            dinv[node] = rsqrtf((float)(dgi + 1));   // +1 self-loop
        }
    }
}

// ---------------- two-level exclusive scan over deg[N] -> rowptr[N+1] ----------------
__global__ __launch_bounds__(256) void k_block_reduce(const int* __restrict__ deg,
                                                      int* __restrict__ partials, int n) {
    __shared__ int red[256];
    int b = blockIdx.x, t = threadIdx.x;
    int base = b * 1024;
    int v = 0;
    for (int i = t; i < 1024; i += 256) {
        int idx = base + i;
        if (idx < n) v += deg[idx];
    }
    red[t] = v; __syncthreads();
    for (int s = 128; s > 0; s >>= 1) { if (t < s) red[t] += red[t + s]; __syncthreads(); }
    if (t == 0) partials[b] = red[0];
}

__global__ void k_scan_partials(int* partials, int nb) {
    if (threadIdx.x == 0 && blockIdx.x == 0) {
        int run = 0;
        for (int i = 0; i < nb; ++i) { int v = partials[i]; partials[i] = run; run += v; }
    }
}

__global__ __launch_bounds__(256) void k_block_scan(const int* __restrict__ deg,
                                                    const int* __restrict__ partials,
                                                    int* __restrict__ rowptr, int n, int etot) {
    __shared__ int red[256];
    int b = blockIdx.x, t = threadIdx.x;
    int base = b * 1024 + t * 4;
    int d[4]; int s = 0;
    for (int j = 0; j < 4; ++j) {
        int idx = base + j;
        d[j] = (idx < n) ? deg[idx] : 0;
        s += d[j];
    }
    red[t] = s; __syncthreads();
    for (int off = 1; off < 256; off <<= 1) {
        int v = (t >= off) ? red[t - off] : 0;
        __syncthreads();
        red[t] += v;
        __syncthreads();
    }
    int excl = partials[b] + (t > 0 ? red[t - 1] : 0);
    for (int j = 0; j < 4; ++j) {
        int idx = base + j;
        if (idx < n) rowptr[idx] = excl;
        excl += d[j];
    }
    if (b == 0 && t == 0) rowptr[n] = etot;
}

// ---------------- pass C: per-bucket scatter into adj (XCD-local writes) ----------------
__global__ __launch_bounds__(256) void k_fill_local(
    const unsigned int* __restrict__ gbuf, const int* __restrict__ gcount,
    const int* __restrict__ rowptr, int* __restrict__ adj, int n)
{
    __shared__ int cursor[RNG];
    const int b = blockIdx.x, tid = threadIdx.x;
    int nbase = b * RNG;
    for (int i = tid; i < RNG; i += 256) {
        int node = nbase + i;
        cursor[i] = (node < n) ? rowptr[node] : 0;
    }
    __syncthreads();
    int cnt = gcount[b];
    const unsigned int* buf = gbuf + (size_t)b * BCAP;
    for (int j = tid; j < cnt; j += 256) {
        unsigned int e = buf[j];
        int dl = e >> 17;
        int s = (int)(e & 0x1FFFFu);
        int pos = atomicAdd(&cursor[dl], 1);
        adj[pos] = s;
    }
}

// ---------------- prep: transposed bf16 weights Wt[64][K] (n-major, k-contiguous) ----------
__global__ void k_prep_w(const float* __restrict__ W1, const float* __restrict__ W2,
                         const float* __restrict__ Wmu, const float* __restrict__ Wlv,
                         unsigned short* __restrict__ Wt1, unsigned short* __restrict__ Wt2,
                         unsigned short* __restrict__ Wtc) {
    int i = blockIdx.x * 256 + threadIdx.x;
    if (i < 64 * 128) {                    // Wt1[nn][kk] = W1[kk][nn]
        int nn = i >> 7, kk = i & 127;
        Wt1[i] = f2bf(W1[kk * 64 + nn]);
    }
    if (i < 64 * 64) {                     // Wt2[nn][kk] = W2[kk][nn]
        int nn = i >> 6, kk = i & 63;
        Wt2[i] = f2bf(W2[kk * 64 + nn]);
        Wtc[i] = f2bf(nn < 32 ? Wmu[kk * 32 + nn] : Wlv[kk * 32 + (nn - 32)]);
    }
}

// ---------------- MFMA GEMM: U(bf16) = transform(A) @ W * dinv[row] ----------------
// TRANS=false: A is f32 [n][K] (input x). TRANS=true: A is bf16 [n][K] (aggregated s),
// transform = relu(s*dinv*alpha + delta). 64 rows/block, 4 waves x (16row x 64col).
// Fragments (16x16x32 bf16): A row=lane&15, k=(lane>>4)*8+j; B col=lane&15, same k;
// D col=lane&15, row=(lane>>4)*4+reg  [m89-verified].
template <int K, bool TRANS>
__global__ __launch_bounds__(256) void k_gemm_mfma(
    const void* __restrict__ Av, const unsigned short* __restrict__ Wt,
    const float* __restrict__ dinv, const float* __restrict__ alpha,
    const float* __restrict__ delta, unsigned short* __restrict__ U, int n)
{
    constexpr int SK = K + 8;                      // padded stride (shorts), 16B-aligned rows
    __shared__ unsigned short As[64 * SK];
    __shared__ unsigned short Ws[64 * SK];
    const int tid = threadIdx.x;
    const int brow = blockIdx.x * 64;
    const int lane = tid & 63, wv = tid >> 6;

    // stage Wt -> Ws (64 x K bf16)
    for (int i = tid; i < 64 * (K / 4); i += 256) {
        int r = i / (K / 4), c4 = i % (K / 4);
        *reinterpret_cast<ushort4*>(&Ws[r * SK + c4 * 4]) =
            reinterpret_cast<const ushort4*>(Wt)[i];
    }
    // stage A -> As (bf16), fusing BN+ReLU transform when TRANS
    for (int i = tid; i < 64 * (K / 4); i += 256) {
        int r = i / (K / 4), c4 = i % (K / 4);
        int grow = brow + r;
        ushort4 o = {0, 0, 0, 0};
        if (grow < n) {
            if (TRANS) {
                uint2 sv = reinterpret_cast<const uint2*>(Av)[(size_t)grow * (K / 4) + c4];
                float f0 = bfbits_lo(sv.x), f1 = bfbits_hi(sv.x);
                float f2 = bfbits_lo(sv.y), f3 = bfbits_hi(sv.y);
                float dv = dinv[grow];
                int c = c4 * 4;
                f0 = fmaxf(fmaf(f0 * dv, alpha[c + 0], delta[c + 0]), 0.f);
                f1 = fmaxf(fmaf(f1 * dv, alpha[c + 1], delta[c + 1]), 0.f);
                f2 = fmaxf(fmaf(f2 * dv, alpha[c + 2], delta[c + 2]), 0.f);
                f3 = fmaxf(fmaf(f3 * dv, alpha[c + 3], delta[c + 3]), 0.f);
                o.x = f2bf(f0); o.y = f2bf(f1); o.z = f2bf(f2); o.w = f2bf(f3);
            } else {
                float4 v = reinterpret_cast<const float4*>(Av)[(size_t)grow * (K / 4) + c4];
                o.x = f2bf(v.x); o.y = f2bf(v.y); o.z = f2bf(v.z); o.w = f2bf(v.w);
            }
        }
        *reinterpret_cast<ushort4*>(&As[r * SK + c4 * 4]) = o;
    }
    __syncthreads();

    f32x4_t acc[4] = {{0.f, 0.f, 0.f, 0.f}, {0.f, 0.f, 0.f, 0.f},
                      {0.f, 0.f, 0.f, 0.f}, {0.f, 0.f, 0.f, 0.f}};
    const int ar = (wv << 4) + (lane & 15);        // A row (this wave's 16-row tile)
    const int kq = (lane >> 4) * 8;                // k sub-offset per quarter
#pragma unroll
    for (int kc = 0; kc < K / 32; ++kc) {
        bf16x8_t a = *reinterpret_cast<const bf16x8_t*>(&As[ar * SK + kc * 32 + kq]);
#pragma unroll
        for (int c = 0; c < 4; ++c) {
            bf16x8_t b = *reinterpret_cast<const bf16x8_t*>(
                &Ws[(c * 16 + (lane & 15)) * SK + kc * 32 + kq]);
            acc[c] = __builtin_amdgcn_mfma_f32_16x16x32_bf16(a, b, acc[c], 0, 0, 0);
        }
    }

    // epilogue: *dinv, bf16, LDS transpose (reuse As as Cs[64][72]), coalesced stores
    unsigned short* Cs = As;
#pragma unroll
    for (int r = 0; r < 4; ++r) {
        int lrow = (wv << 4) + ((lane >> 4) << 2) + r;
        int grow = brow + lrow;
        float dv = (grow < n) ? dinv[grow] : 0.f;
#pragma unroll
        for (int c = 0; c < 4; ++c)
            Cs[lrow * 72 + c * 16 + (lane & 15)] = f2bf(acc[c][r] * dv);
    }
    __syncthreads();
    for (int i = tid; i < 64 * 8; i += 256) {
        int r = i >> 3, g = i & 7;
        int grow = brow + r;
        if (grow < n)
            *reinterpret_cast<uint4*>(&U[(size_t)grow * 64 + g * 8]) =
                *reinterpret_cast<const uint4*>(&Cs[r * 72 + g * 8]);
    }
}

// ---------------- quarter-wave gather: lane = 16*q + f16, 4 features (1 uint2) per lane ----
// Quarter q handles local edge indices i = q + 4t, wave-uniform trip count (R5 bug fix).
__device__ inline void gather_row4(const int* __restrict__ rowptr, const int* __restrict__ adj,
                                   const uint2* __restrict__ u2, int node, int lane, int q, int f16,
                                   f32x2_t& a01, f32x2_t& a23)
{
    int beg = rowptr[node], end = rowptr[node + 1];
    for (int cbeg = beg; cbeg < end; cbeg += 64) {
        int cnt = min(64, end - cbeg);        // wave-uniform
        int a = (lane < cnt) ? adj[cbeg + lane] : 0;
        int T = (cnt + 3) >> 2;               // wave-uniform trips per quarter
        int t = 0, i = q;
        for (; t + 4 <= T; t += 4, i += 16) {
            int s0 = __shfl(a, i);
            int s1 = __shfl(a, i + 4);
            int s2 = __shfl(a, i + 8);
            int s3 = __shfl(a, i + 12);
            uint2 v0 = u2[(size_t)s0 * 16 + f16];
            uint2 v1 = u2[(size_t)s1 * 16 + f16];
            uint2 v2 = u2[(size_t)s2 * 16 + f16];
            uint2 v3 = u2[(size_t)s3 * 16 + f16];
            if (i      >= cnt) { v0.x = 0u; v0.y = 0u; }
            if (i + 4  >= cnt) { v1.x = 0u; v1.y = 0u; }
            if (i + 8  >= cnt) { v2.x = 0u; v2.y = 0u; }
            if (i + 12 >= cnt) { v3.x = 0u; v3.y = 0u; }
            addpk2(a01, a23, v0); addpk2(a01, a23, v1);
            addpk2(a01, a23, v2); addpk2(a01, a23, v3);
        }
        for (; t < T; ++t, i += 4) {
            int s = __shfl(a, i);
            uint2 v = u2[(size_t)s * 16 + f16];
            if (i >= cnt) { v.x = 0u; v.y = 0u; }
            addpk2(a01, a23, v);
        }
    }
}

// ---------------- aggregate, grid-stride; MODE 0: write s(bf16) + fused BN partial stats
// ----------------                         MODE 1: final epilogue -> out = [mu ; logvar]
template <int MODE>
__global__ __launch_bounds__(256) void k_agg4(
    const int* __restrict__ rowptr, const int* __restrict__ adj,
    const uint2* __restrict__ u2, const float* __restrict__ dinv,
    const float* __restrict__ bias,
    const float* __restrict__ bmu, const float* __restrict__ blv,
    unsigned short* __restrict__ sout, float* __restrict__ outp,
    float* __restrict__ pblk, int n)
{
    const int tid = threadIdx.x;
    const int lane = tid & 63;
    const int q = lane >> 4, f16 = lane & 15;
    const int wv = tid >> 6;
    const int wid = (blockIdx.x * 256 + tid) >> 6;
    const int nw = (gridDim.x * 256) >> 6;

    float4 bb;
    if (MODE == 0) {
        bb = *reinterpret_cast<const float4*>(&bias[f16 * 4]);
    } else {
        bb = (f16 < 8) ? *reinterpret_cast<const float4*>(&bmu[f16 * 4])
                       : *reinterpret_cast<const float4*>(&blv[(f16 - 8) * 4]);
    }

    float ls[4] = {0.f, 0.f, 0.f, 0.f}, lq[4] = {0.f, 0.f, 0.f, 0.f};

    for (int node = wid; node < n; node += nw) {
        f32x2_t a01 = {0.f, 0.f}, a23 = {0.f, 0.f};
        gather_row4(rowptr, adj, u2, node, lane, q, f16, a01, a23);
        if (q == 0) {
            addpk2(a01, a23, u2[(size_t)node * 16 + f16]);   // self-loop
        }
        // cross-quarter reduce (all lanes active)
        a01.x += __shfl_xor(a01.x, 16); a01.x += __shfl_xor(a01.x, 32);
        a01.y += __shfl_xor(a01.y, 16); a01.y += __shfl_xor(a01.y, 32);
        a23.x += __shfl_xor(a23.x, 16); a23.x += __shfl_xor(a23.x, 32);
        a23.y += __shfl_xor(a23.y, 16); a23.y += __shfl_xor(a23.y, 32);
        if (q == 0) {
            if (MODE == 0) {
                uint2 o;
                o.x = (unsigned)f2bf(a01.x) | ((unsigned)f2bf(a01.y) << 16);
                o.y = (unsigned)f2bf(a23.x) | ((unsigned)f2bf(a23.y) << 16);
                reinterpret_cast<uint2*>(sout)[(size_t)node * 16 + f16] = o;
                float dv = dinv[node];
                float y0 = fmaf(a01.x, dv, bb.x); ls[0] += y0; lq[0] = fmaf(y0, y0, lq[0]);
                float y1 = fmaf(a01.y, dv, bb.y); ls[1] += y1; lq[1] = fmaf(y1, y1, lq[1]);
                float y2 = fmaf(a23.x, dv, bb.z); ls[2] += y2; lq[2] = fmaf(y2, y2, lq[2]);
                float y3 = fmaf(a23.y, dv, bb.w); ls[3] += y3; lq[3] = fmaf(y3, y3, lq[3]);
            } else {
                float dv = dinv[node];
                float4 o = {fmaf(a01.x, dv, bb.x), fmaf(a01.y, dv, bb.y),
                            fmaf(a23.x, dv, bb.z), fmaf(a23.y, dv, bb.w)};
                size_t total = (size_t)n * 32;
                float* dst = (f16 < 8) ? &outp[(size_t)node * 32 + f16 * 4]
                                       : &outp[total + (size_t)node * 32 + (f16 - 8) * 4];
                *reinterpret_cast<float4*>(dst) = o;
            }
        }
    }

    if (MODE == 0) {
        __shared__ float red[4][128];
        if (q == 0) {
#pragma unroll
            for (int j = 0; j < 4; ++j) {
                red[wv][f16 * 4 + j] = ls[j];
                red[wv][64 + f16 * 4 + j] = lq[j];
            }
        }
        __syncthreads();
        if (tid < 128) {
            float v = red[0][tid] + red[1][tid] + red[2][tid] + red[3][tid];
            pblk[(size_t)blockIdx.x * 128 + tid] = v;
        }
    }
}

// ---------------- stage-1 tree reduce: pblk[nb][128] -> pblk2[NRED][128] ----------------
__global__ __launch_bounds__(256) void k_reduce_pblk(
    const float* __restrict__ pblk, float* __restrict__ pblk2, int nb)
{
    __shared__ float red[2][128];
    int b = blockIdx.x, t = threadIdx.x;
    int col = t & 127, rg = t >> 7;
    int rows = nb / NRED;
    int base = b * rows;
    float s = 0.f;
    for (int r = rg; r < rows; r += 2) s += pblk[(size_t)(base + r) * 128 + col];
    red[rg][col] = s;
    __syncthreads();
    if (t < 128) pblk2[(size_t)b * 128 + t] = red[0][t] + red[1][t];
}

// ---------------- reduce pblk2 -> alpha/delta ----------------
__global__ __launch_bounds__(256) void k_bn_finalize2(
    const float* __restrict__ pblk, int nb,
    const float* __restrict__ g, const float* __restrict__ be,
    const float* __restrict__ b, float* __restrict__ alpha,
    float* __restrict__ delta, int n)
{
    __shared__ float tmp[256];
    __shared__ float stats[128];
    int t = threadIdx.x;
    int col = t & 127, half = t >> 7;
    float s = 0.f;
    for (int b2 = half; b2 < nb; b2 += 2) s += pblk[(size_t)b2 * 128 + col];
    tmp[t] = s; __syncthreads();
    if (t < 128) stats[t] = tmp[t] + tmp[t + 128];
    __syncthreads();
    if (t < 64) {
        float mu = stats[t] / (float)n;
        float var = stats[64 + t] / (float)n - mu * mu;
        float inv = rsqrtf(var + 1e-5f);
        float a = inv * g[t];
        alpha[t] = a;
        delta[t] = fmaf(b[t] - mu, a, be[t]);
    }
}

extern "C" void kernel_launch(void* const* d_in, const int* in_sizes, int n_in,
                              void* d_out, int out_size, void* d_ws, size_t ws_size,
                              hipStream_t stream) {
    const int N = NNODES, E = NEDGES;

    const float* x   = (const float*)d_in[0];
    const int* ei    = (const int*)d_in[1];
    const float* W1  = (const float*)d_in[2];
    const float* b1  = (const float*)d_in[3];
    const float* g1  = (const float*)d_in[4];
    const float* be1 = (const float*)d_in[5];
    const float* W2  = (const float*)d_in[6];
    const float* b2  = (const float*)d_in[7];
    const float* g2  = (const float*)d_in[8];
    const float* be2 = (const float*)d_in[9];
    const float* Wmu = (const float*)d_in[10];
    const float* bmu = (const float*)d_in[11];
    const float* Wlv = (const float*)d_in[12];
    const float* blv = (const float*)d_in[13];
    float* out = (float*)d_out;

    const int* src = ei;
    const int* dst = ei + E;

    char* ws = (char*)d_ws;
    size_t off = 0;
    auto alloc = [&](size_t bytes) { char* p = ws + off; off += (bytes + 255) & ~(size_t)255; return p; };
    float*          dinv   = (float*)alloc((size_t)N * 4);
    unsigned short* bufU   = (unsigned short*)alloc((size_t)N * 64 * 2);
    unsigned short* bufS   = (unsigned short*)alloc((size_t)N * 64 * 2);
    int*            degi   = (int*)alloc((size_t)N * 4);
    int*            rowptr = (int*)alloc((size_t)(N + 1) * 4);
    int*            adj    = (int*)alloc((size_t)E * 4);
    unsigned int*   gbuf   = (unsigned int*)alloc((size_t)KBUCK * BCAP * 4);
    int*            gcount = (int*)alloc((size_t)KBUCK * 4);
    int*            partials = (int*)alloc(128 * 4);
    float*          pblk   = (float*)alloc((size_t)NBAGG * 128 * 4);
    float*          pblk2  = (float*)alloc((size_t)NRED * 128 * 4);
    unsigned short* Wt1    = (unsigned short*)alloc(64 * 128 * 2);
    unsigned short* Wt2    = (unsigned short*)alloc(64 * 64 * 2);
    unsigned short* Wtc    = (unsigned short*)alloc(64 * 64 * 2);
    float*          alpha  = (float*)alloc(64 * 4);
    float*          delta  = (float*)alloc(64 * 4);
    (void)ws_size;

    const int B = 256;
    dim3 blk(B);
    int gGemm  = (N + 63) / 64;           // 1563
    int gScan  = (N + 1023) / 1024;       // 98
    int gBin   = (E + CHUNK - 1) / CHUNK; // 391
    const uint2* u2 = (const uint2*)bufU;

    // ---- build CSR: bin -> hist/dinv -> scan -> local fill ----
    hipMemsetAsync(gcount, 0, (size_t)KBUCK * 4, stream);
    k_bin<<<gBin, blk, 0, stream>>>(src, dst, gbuf, gcount, E);
    k_hist_dinv<<<KBUCK, blk, 0, stream>>>(gbuf, gcount, degi, dinv, N);
    k_block_reduce<<<gScan, blk, 0, stream>>>(degi, partials, N);
    k_scan_partials<<<1, 64, 0, stream>>>(partials, gScan);
    k_block_scan<<<gScan, blk, 0, stream>>>(degi, partials, rowptr, N, E);
    k_fill_local<<<KBUCK, blk, 0, stream>>>(gbuf, gcount, rowptr, adj, N);
    k_prep_w<<<32, blk, 0, stream>>>(W1, W2, Wmu, Wlv, Wt1, Wt2, Wtc);

    // ---- layer 1 ----
    k_gemm_mfma<128, false><<<gGemm, blk, 0, stream>>>(x, Wt1, dinv, nullptr, nullptr, bufU, N);
    k_agg4<0><<<NBAGG, blk, 0, stream>>>(rowptr, adj, u2, dinv, b1, nullptr, nullptr,
                                         bufS, nullptr, pblk, N);
    k_reduce_pblk<<<NRED, blk, 0, stream>>>(pblk, pblk2, NBAGG);
    k_bn_finalize2<<<1, blk, 0, stream>>>(pblk2, NRED, g1, be1, b1, alpha, delta, N);

    // ---- layer 2 ----
    k_gemm_mfma<64, true><<<gGemm, blk, 0, stream>>>(bufS, Wt2, dinv, alpha, delta, bufU, N);
    k_agg4<0><<<NBAGG, blk, 0, stream>>>(rowptr, adj, u2, dinv, b2, nullptr, nullptr,
                                         bufS, nullptr, pblk, N);
    k_reduce_pblk<<<NRED, blk, 0, stream>>>(pblk, pblk2, NBAGG);
    k_bn_finalize2<<<1, blk, 0, stream>>>(pblk2, NRED, g2, be2, b2, alpha, delta, N);

    // ---- heads (mu ‖ logvar fused) + final epilogue ----
    k_gemm_mfma<64, true><<<gGemm, blk, 0, stream>>>(bufS, Wtc, dinv, alpha, delta, bufU, N);
    k_agg4<1><<<NBAGG, blk, 0, stream>>>(rowptr, adj, u2, dinv, nullptr, bmu, blv,
                                         nullptr, out, nullptr, N);
}

// Round 10
// 254.957 us; speedup vs baseline: 1.0573x; 1.0573x over previous
//
#include <hip/hip_runtime.h>

#define NNODES 100000
#define NEDGES 1600000
#define KBUCK 196          // ceil(N / 512)
#define RNG 512            // nodes per bucket (dst >> 9)
#define BCAP 9216          // bucket capacity: mean 8192, sd ~90 -> 11 sigma headroom
#define CHUNK 4096         // edges per workgroup in binning pass
#define NBAGG 2048         // aggregate grid (8192 waves -> 8 waves/SIMD)
#define NRED 128           // stage-1 reduction blocks for pblk

typedef __attribute__((ext_vector_type(8))) short bf16x8_t;   // 8 bf16 (4 VGPR)
typedef __attribute__((ext_vector_type(4))) float f32x4_t;    // MFMA acc
typedef __attribute__((ext_vector_type(2))) float f32x2_t;    // packed-f32 pair (v_pk_add_f32)

// ---- bf16 helpers (RNE) ----
__device__ inline unsigned short f2bf(float f) {
    union { float f; unsigned u; } a; a.f = f;
    unsigned r = (a.u + 0x7FFFu + ((a.u >> 16) & 1u)) >> 16;
    return (unsigned short)r;
}
__device__ inline float bfbits_lo(unsigned u) {
    union { unsigned u; float f; } a; a.u = u << 16; return a.f;
}
__device__ inline float bfbits_hi(unsigned u) {
    union { unsigned u; float f; } a; a.u = u & 0xFFFF0000u; return a.f;
}

// unpack uint2 (4 bf16) and add into two f32 pairs (compiler may emit v_pk_add_f32)
__device__ inline void addpk2(f32x2_t& a01, f32x2_t& a23, uint2 v) {
    f32x2_t d0, d1;
    d0.x = bfbits_lo(v.x); d0.y = bfbits_hi(v.x);
    d1.x = bfbits_lo(v.y); d1.y = bfbits_hi(v.y);
    a01 += d0; a23 += d1;
}

// ---------------- pass A: bin edges by dst>>9 into KBUCK buckets (LDS-staged) ----------------
__global__ __launch_bounds__(256) void k_bin(
    const int* __restrict__ src, const int* __restrict__ dst,
    unsigned int* __restrict__ gbuf, int* __restrict__ gcount, int e)
{
    __shared__ unsigned int bins[KBUCK][64];
    __shared__ int bcount[KBUCK];
    const int tid = threadIdx.x;
    for (int i = tid; i < KBUCK; i += 256) bcount[i] = 0;
    __syncthreads();

    int base = blockIdx.x * CHUNK;
    int lim = min(e, base + CHUNK);
    for (int i = base + tid; i < lim; i += 256) {
        int d = dst[i];
        int s = src[i];
        int b = d >> 9;
        unsigned int entry = ((unsigned int)(d & 511) << 17) | (unsigned int)s;
        int idx = atomicAdd(&bcount[b], 1);
        if (idx < 64) {
            bins[b][idx] = entry;
        } else {
            int gpos = atomicAdd(&gcount[b], 1);
            if (gpos < BCAP) gbuf[(size_t)b * BCAP + gpos] = entry;
        }
    }
    __syncthreads();

    for (int b = tid; b < KBUCK; b += 256) {
        int n = min(bcount[b], 64);
        if (n > 0) {
            int pos = atomicAdd(&gcount[b], n);
            int m = min(n, BCAP - pos);
            for (int i = 0; i < m; ++i)
                gbuf[(size_t)b * BCAP + pos + i] = bins[b][i];
        }
    }
}

// ---------------- pass B: per-bucket degree histogram -> deg + dinv ----------------
__global__ __launch_bounds__(256) void k_hist_dinv(
    const unsigned int* __restrict__ gbuf, const int* __restrict__ gcount,
    int* __restrict__ deg, float* __restrict__ dinv, int n)
{
    __shared__ int hist[RNG];
    const int b = blockIdx.x, tid = threadIdx.x;
    for (int i = tid; i < RNG; i += 256) hist[i] = 0;
    __syncthreads();
    int cnt = gcount[b];
    const unsigned int* buf = gbuf + (size_t)b * BCAP;
    for (int j = tid; j < cnt; j += 256)
        atomicAdd(&hist[buf[j] >> 17], 1);
    __syncthreads();
    int nbase = b * RNG;
    for (int i = tid; i < RNG; i += 256) {
        int node = nbase + i;
        if (node < n) {
            int dgi = hist[i];
            deg[node] = dgi;
            dinv[node] = rsqrtf((float)(dgi + 1));   // +1 self-loop
        }
    }
}

// ---------------- two-level exclusive scan over deg[N] -> rowptr[N+1] ----------------
__global__ __launch_bounds__(256) void k_block_reduce(const int* __restrict__ deg,
                                                      int* __restrict__ partials, int n) {
    __shared__ int red[256];
    int b = blockIdx.x, t = threadIdx.x;
    int base = b * 1024;
    int v = 0;
    for (int i = t; i < 1024; i += 256) {
        int idx = base + i;
        if (idx < n) v += deg[idx];
    }
    red[t] = v; __syncthreads();
    for (int s = 128; s > 0; s >>= 1) { if (t < s) red[t] += red[t + s]; __syncthreads(); }
    if (t == 0) partials[b] = red[0];
}

__global__ void k_scan_partials(int* partials, int nb) {
    if (threadIdx.x == 0 && blockIdx.x == 0) {
        int run = 0;
        for (int i = 0; i < nb; ++i) { int v = partials[i]; partials[i] = run; run += v; }
    }
}

__global__ __launch_bounds__(256) void k_block_scan(const int* __restrict__ deg,
                                                    const int* __restrict__ partials,
                                                    int* __restrict__ rowptr, int n, int etot) {
    __shared__ int red[256];
    int b = blockIdx.x, t = threadIdx.x;
    int base = b * 1024 + t * 4;
    int d[4]; int s = 0;
    for (int j = 0; j < 4; ++j) {
        int idx = base + j;
        d[j] = (idx < n) ? deg[idx] : 0;
        s += d[j];
    }
    red[t] = s; __syncthreads();
    for (int off = 1; off < 256; off <<= 1) {
        int v = (t >= off) ? red[t - off] : 0;
        __syncthreads();
        red[t] += v;
        __syncthreads();
    }
    int excl = partials[b] + (t > 0 ? red[t - 1] : 0);
    for (int j = 0; j < 4; ++j) {
        int idx = base + j;
        if (idx < n) rowptr[idx] = excl;
        excl += d[j];
    }
    if (b == 0 && t == 0) rowptr[n] = etot;
}

// ---------------- pass C: per-bucket scatter into adj (XCD-local writes) ----------------
__global__ __launch_bounds__(256) void k_fill_local(
    const unsigned int* __restrict__ gbuf, const int* __restrict__ gcount,
    const int* __restrict__ rowptr, int* __restrict__ adj, int n)
{
    __shared__ int cursor[RNG];
    const int b = blockIdx.x, tid = threadIdx.x;
    int nbase = b * RNG;
    for (int i = tid; i < RNG; i += 256) {
        int node = nbase + i;
        cursor[i] = (node < n) ? rowptr[node] : 0;
    }
    __syncthreads();
    int cnt = gcount[b];
    const unsigned int* buf = gbuf + (size_t)b * BCAP;
    for (int j = tid; j < cnt; j += 256) {
        unsigned int e = buf[j];
        int dl = e >> 17;
        int s = (int)(e & 0x1FFFFu);
        int pos = atomicAdd(&cursor[dl], 1);
        adj[pos] = s;
    }
}

// ---------------- prep: transposed bf16 weights Wt[64][K] (n-major, k-contiguous) ----------
__global__ void k_prep_w(const float* __restrict__ W1, const float* __restrict__ W2,
                         const float* __restrict__ Wmu, const float* __restrict__ Wlv,
                         unsigned short* __restrict__ Wt1, unsigned short* __restrict__ Wt2,
                         unsigned short* __restrict__ Wtc) {
    int i = blockIdx.x * 256 + threadIdx.x;
    if (i < 64 * 128) {                    // Wt1[nn][kk] = W1[kk][nn]
        int nn = i >> 7, kk = i & 127;
        Wt1[i] = f2bf(W1[kk * 64 + nn]);
    }
    if (i < 64 * 64) {                     // Wt2[nn][kk] = W2[kk][nn]
        int nn = i >> 6, kk = i & 63;
        Wt2[i] = f2bf(W2[kk * 64 + nn]);
        Wtc[i] = f2bf(nn < 32 ? Wmu[kk * 32 + nn] : Wlv[kk * 32 + (nn - 32)]);
    }
}

// ---------------- MFMA GEMM: U(bf16) = transform(A) @ W * dinv[row] ----------------
// TRANS=false: A is f32 [n][K] (input x). TRANS=true: A is bf16 [n][K] (aggregated s),
// transform = relu(s*dinv*alpha + delta). 64 rows/block, 4 waves x (16row x 64col).
template <int K, bool TRANS>
__global__ __launch_bounds__(256) void k_gemm_mfma(
    const void* __restrict__ Av, const unsigned short* __restrict__ Wt,
    const float* __restrict__ dinv, const float* __restrict__ alpha,
    const float* __restrict__ delta, unsigned short* __restrict__ U, int n)
{
    constexpr int SK = K + 8;                      // padded stride (shorts), 16B-aligned rows
    __shared__ unsigned short As[64 * SK];
    __shared__ unsigned short Ws[64 * SK];
    const int tid = threadIdx.x;
    const int brow = blockIdx.x * 64;
    const int lane = tid & 63, wv = tid >> 6;

    for (int i = tid; i < 64 * (K / 4); i += 256) {
        int r = i / (K / 4), c4 = i % (K / 4);
        *reinterpret_cast<ushort4*>(&Ws[r * SK + c4 * 4]) =
            reinterpret_cast<const ushort4*>(Wt)[i];
    }
    for (int i = tid; i < 64 * (K / 4); i += 256) {
        int r = i / (K / 4), c4 = i % (K / 4);
        int grow = brow + r;
        ushort4 o = {0, 0, 0, 0};
        if (grow < n) {
            if (TRANS) {
                uint2 sv = reinterpret_cast<const uint2*>(Av)[(size_t)grow * (K / 4) + c4];
                float f0 = bfbits_lo(sv.x), f1 = bfbits_hi(sv.x);
                float f2 = bfbits_lo(sv.y), f3 = bfbits_hi(sv.y);
                float dv = dinv[grow];
                int c = c4 * 4;
                f0 = fmaxf(fmaf(f0 * dv, alpha[c + 0], delta[c + 0]), 0.f);
                f1 = fmaxf(fmaf(f1 * dv, alpha[c + 1], delta[c + 1]), 0.f);
                f2 = fmaxf(fmaf(f2 * dv, alpha[c + 2], delta[c + 2]), 0.f);
                f3 = fmaxf(fmaf(f3 * dv, alpha[c + 3], delta[c + 3]), 0.f);
                o.x = f2bf(f0); o.y = f2bf(f1); o.z = f2bf(f2); o.w = f2bf(f3);
            } else {
                float4 v = reinterpret_cast<const float4*>(Av)[(size_t)grow * (K / 4) + c4];
                o.x = f2bf(v.x); o.y = f2bf(v.y); o.z = f2bf(v.z); o.w = f2bf(v.w);
            }
        }
        *reinterpret_cast<ushort4*>(&As[r * SK + c4 * 4]) = o;
    }
    __syncthreads();

    f32x4_t acc[4] = {{0.f, 0.f, 0.f, 0.f}, {0.f, 0.f, 0.f, 0.f},
                      {0.f, 0.f, 0.f, 0.f}, {0.f, 0.f, 0.f, 0.f}};
    const int ar = (wv << 4) + (lane & 15);
    const int kq = (lane >> 4) * 8;
#pragma unroll
    for (int kc = 0; kc < K / 32; ++kc) {
        bf16x8_t a = *reinterpret_cast<const bf16x8_t*>(&As[ar * SK + kc * 32 + kq]);
#pragma unroll
        for (int c = 0; c < 4; ++c) {
            bf16x8_t b = *reinterpret_cast<const bf16x8_t*>(
                &Ws[(c * 16 + (lane & 15)) * SK + kc * 32 + kq]);
            acc[c] = __builtin_amdgcn_mfma_f32_16x16x32_bf16(a, b, acc[c], 0, 0, 0);
        }
    }

    unsigned short* Cs = As;
#pragma unroll
    for (int r = 0; r < 4; ++r) {
        int lrow = (wv << 4) + ((lane >> 4) << 2) + r;
        int grow = brow + lrow;
        float dv = (grow < n) ? dinv[grow] : 0.f;
#pragma unroll
        for (int c = 0; c < 4; ++c)
            Cs[lrow * 72 + c * 16 + (lane & 15)] = f2bf(acc[c][r] * dv);
    }
    __syncthreads();
    for (int i = tid; i < 64 * 8; i += 256) {
        int r = i >> 3, g = i & 7;
        int grow = brow + r;
        if (grow < n)
            *reinterpret_cast<uint4*>(&U[(size_t)grow * 64 + g * 8]) =
                *reinterpret_cast<const uint4*>(&Cs[r * 72 + g * 8]);
    }
}

// ---------------- paired quarter-wave gather: two adjacent nodes per wave ----------------
// R9 post-mortem: per-node serial chain rowptr->adj->shfl->u barely overlaps across nodes
// (1000 cyc/node-slot measured). Processing a node PAIR amortizes the head chain 2x and
// keeps 4 u-loads in flight (2 streams x 2-deep) without exceeding 64 VGPR (m69 cliff).
// All __shfl sites remain wave-uniform (Tm = max of the two trip counts); when one stream
// runs past its cnt, the shuffled index lane holds 0 -> safe row-0 load, value masked to 0.
__device__ inline void gather_pair(const int* __restrict__ rowptr, const int* __restrict__ adj,
                                   const uint2* __restrict__ u2, int nodeA, int lane, int q, int f16,
                                   f32x2_t& a01, f32x2_t& a23, f32x2_t& b01, f32x2_t& b23)
{
    int begA = rowptr[nodeA];
    int mid  = rowptr[nodeA + 1];
    int endB = rowptr[nodeA + 2];
    for (int cA = begA, cB = mid; cA < mid || cB < endB; cA += 64, cB += 64) {
        int cntA = max(0, min(64, mid - cA));
        int cntB = max(0, min(64, endB - cB));
        int aA = (lane < cntA) ? adj[cA + lane] : 0;
        int aB = (lane < cntB) ? adj[cB + lane] : 0;
        int Tm = (max(cntA, cntB) + 3) >> 2;       // wave-uniform trips per quarter
        int t = 0, i = q;
        for (; t + 2 <= Tm; t += 2, i += 8) {      // 2A + 2B loads in flight
            int sA0 = __shfl(aA, i), sA1 = __shfl(aA, i + 4);
            int sB0 = __shfl(aB, i), sB1 = __shfl(aB, i + 4);
            uint2 vA0 = u2[(size_t)sA0 * 16 + f16];
            uint2 vB0 = u2[(size_t)sB0 * 16 + f16];
            uint2 vA1 = u2[(size_t)sA1 * 16 + f16];
            uint2 vB1 = u2[(size_t)sB1 * 16 + f16];
            if (i     >= cntA) { vA0.x = 0u; vA0.y = 0u; }
            if (i + 4 >= cntA) { vA1.x = 0u; vA1.y = 0u; }
            if (i     >= cntB) { vB0.x = 0u; vB0.y = 0u; }
            if (i + 4 >= cntB) { vB1.x = 0u; vB1.y = 0u; }
            addpk2(a01, a23, vA0); addpk2(b01, b23, vB0);
            addpk2(a01, a23, vA1); addpk2(b01, b23, vB1);
        }
        for (; t < Tm; ++t, i += 4) {
            int sA = __shfl(aA, i), sB = __shfl(aB, i);
            uint2 vA = u2[(size_t)sA * 16 + f16];
            uint2 vB = u2[(size_t)sB * 16 + f16];
            if (i >= cntA) { vA.x = 0u; vA.y = 0u; }
            if (i >= cntB) { vB.x = 0u; vB.y = 0u; }
            addpk2(a01, a23, vA); addpk2(b01, b23, vB);
        }
    }
}

// ---------------- aggregate, grid-stride over node PAIRS; MODE 0: s(bf16) + BN stats
// ----------------                                          MODE 1: out = [mu ; logvar]
template <int MODE>
__global__ __launch_bounds__(256) void k_agg4(
    const int* __restrict__ rowptr, const int* __restrict__ adj,
    const uint2* __restrict__ u2, const float* __restrict__ dinv,
    const float* __restrict__ bias,
    const float* __restrict__ bmu, const float* __restrict__ blv,
    unsigned short* __restrict__ sout, float* __restrict__ outp,
    float* __restrict__ pblk, int n)
{
    const int tid = threadIdx.x;
    const int lane = tid & 63;
    const int q = lane >> 4, f16 = lane & 15;
    const int wv = tid >> 6;
    const int wid = (blockIdx.x * 256 + tid) >> 6;
    const int nw = (gridDim.x * 256) >> 6;
    const int half = n >> 1;                       // N is even (100000)

    float4 bb;
    if (MODE == 0) {
        bb = *reinterpret_cast<const float4*>(&bias[f16 * 4]);
    } else {
        bb = (f16 < 8) ? *reinterpret_cast<const float4*>(&bmu[f16 * 4])
                       : *reinterpret_cast<const float4*>(&blv[(f16 - 8) * 4]);
    }

    float ls[4] = {0.f, 0.f, 0.f, 0.f}, lq[4] = {0.f, 0.f, 0.f, 0.f};

    for (int base = wid; base < half; base += nw) {
        const int nodeA = base * 2, nodeB = nodeA + 1;
        f32x2_t a01 = {0.f, 0.f}, a23 = {0.f, 0.f};
        f32x2_t b01 = {0.f, 0.f}, b23 = {0.f, 0.f};
        gather_pair(rowptr, adj, u2, nodeA, lane, q, f16, a01, a23, b01, b23);
        if (q == 0) {
            addpk2(a01, a23, u2[(size_t)nodeA * 16 + f16]);   // self-loops
            addpk2(b01, b23, u2[(size_t)nodeB * 16 + f16]);
        }
        // cross-quarter reduce (all lanes active)
        a01.x += __shfl_xor(a01.x, 16); a01.x += __shfl_xor(a01.x, 32);
        a01.y += __shfl_xor(a01.y, 16); a01.y += __shfl_xor(a01.y, 32);
        a23.x += __shfl_xor(a23.x, 16); a23.x += __shfl_xor(a23.x, 32);
        a23.y += __shfl_xor(a23.y, 16); a23.y += __shfl_xor(a23.y, 32);
        b01.x += __shfl_xor(b01.x, 16); b01.x += __shfl_xor(b01.x, 32);
        b01.y += __shfl_xor(b01.y, 16); b01.y += __shfl_xor(b01.y, 32);
        b23.x += __shfl_xor(b23.x, 16); b23.x += __shfl_xor(b23.x, 32);
        b23.y += __shfl_xor(b23.y, 16); b23.y += __shfl_xor(b23.y, 32);
        if (q == 0) {
            if (MODE == 0) {
                uint2 oA, oB;
                oA.x = (unsigned)f2bf(a01.x) | ((unsigned)f2bf(a01.y) << 16);
                oA.y = (unsigned)f2bf(a23.x) | ((unsigned)f2bf(a23.y) << 16);
                oB.x = (unsigned)f2bf(b01.x) | ((unsigned)f2bf(b01.y) << 16);
                oB.y = (unsigned)f2bf(b23.x) | ((unsigned)f2bf(b23.y) << 16);
                reinterpret_cast<uint2*>(sout)[(size_t)nodeA * 16 + f16] = oA;
                reinterpret_cast<uint2*>(sout)[(size_t)nodeB * 16 + f16] = oB;
                float dvA = dinv[nodeA], dvB = dinv[nodeB];
                float y;
                y = fmaf(a01.x, dvA, bb.x); ls[0] += y; lq[0] = fmaf(y, y, lq[0]);
                y = fmaf(a01.y, dvA, bb.y); ls[1] += y; lq[1] = fmaf(y, y, lq[1]);
                y = fmaf(a23.x, dvA, bb.z); ls[2] += y; lq[2] = fmaf(y, y, lq[2]);
                y = fmaf(a23.y, dvA, bb.w); ls[3] += y; lq[3] = fmaf(y, y, lq[3]);
                y = fmaf(b01.x, dvB, bb.x); ls[0] += y; lq[0] = fmaf(y, y, lq[0]);
                y = fmaf(b01.y, dvB, bb.y); ls[1] += y; lq[1] = fmaf(y, y, lq[1]);
                y = fmaf(b23.x, dvB, bb.z); ls[2] += y; lq[2] = fmaf(y, y, lq[2]);
                y = fmaf(b23.y, dvB, bb.w); ls[3] += y; lq[3] = fmaf(y, y, lq[3]);
            } else {
                float dvA = dinv[nodeA], dvB = dinv[nodeB];
                size_t total = (size_t)n * 32;
                float4 oA = {fmaf(a01.x, dvA, bb.x), fmaf(a01.y, dvA, bb.y),
                             fmaf(a23.x, dvA, bb.z), fmaf(a23.y, dvA, bb.w)};
                float4 oB = {fmaf(b01.x, dvB, bb.x), fmaf(b01.y, dvB, bb.y),
                             fmaf(b23.x, dvB, bb.z), fmaf(b23.y, dvB, bb.w)};
                if (f16 < 8) {
                    *reinterpret_cast<float4*>(&outp[(size_t)nodeA * 32 + f16 * 4]) = oA;
                    *reinterpret_cast<float4*>(&outp[(size_t)nodeB * 32 + f16 * 4]) = oB;
                } else {
                    *reinterpret_cast<float4*>(&outp[total + (size_t)nodeA * 32 + (f16 - 8) * 4]) = oA;
                    *reinterpret_cast<float4*>(&outp[total + (size_t)nodeB * 32 + (f16 - 8) * 4]) = oB;
                }
            }
        }
    }

    if (MODE == 0) {
        __shared__ float red[4][128];
        if (q == 0) {
#pragma unroll
            for (int j = 0; j < 4; ++j) {
                red[wv][f16 * 4 + j] = ls[j];
                red[wv][64 + f16 * 4 + j] = lq[j];
            }
        }
        __syncthreads();
        if (tid < 128) {
            float v = red[0][tid] + red[1][tid] + red[2][tid] + red[3][tid];
            pblk[(size_t)blockIdx.x * 128 + tid] = v;
        }
    }
}

// ---------------- stage-1 tree reduce: pblk[nb][128] -> pblk2[NRED][128] ----------------
__global__ __launch_bounds__(256) void k_reduce_pblk(
    const float* __restrict__ pblk, float* __restrict__ pblk2, int nb)
{
    __shared__ float red[2][128];
    int b = blockIdx.x, t = threadIdx.x;
    int col = t & 127, rg = t >> 7;
    int rows = nb / NRED;
    int base = b * rows;
    float s = 0.f;
    for (int r = rg; r < rows; r += 2) s += pblk[(size_t)(base + r) * 128 + col];
    red[rg][col] = s;
    __syncthreads();
    if (t < 128) pblk2[(size_t)b * 128 + t] = red[0][t] + red[1][t];
}

// ---------------- reduce pblk2 -> alpha/delta ----------------
__global__ __launch_bounds__(256) void k_bn_finalize2(
    const float* __restrict__ pblk, int nb,
    const float* __restrict__ g, const float* __restrict__ be,
    const float* __restrict__ b, float* __restrict__ alpha,
    float* __restrict__ delta, int n)
{
    __shared__ float tmp[256];
    __shared__ float stats[128];
    int t = threadIdx.x;
    int col = t & 127, half = t >> 7;
    float s = 0.f;
    for (int b2 = half; b2 < nb; b2 += 2) s += pblk[(size_t)b2 * 128 + col];
    tmp[t] = s; __syncthreads();
    if (t < 128) stats[t] = tmp[t] + tmp[t + 128];
    __syncthreads();
    if (t < 64) {
        float mu = stats[t] / (float)n;
        float var = stats[64 + t] / (float)n - mu * mu;
        float inv = rsqrtf(var + 1e-5f);
        float a = inv * g[t];
        alpha[t] = a;
        delta[t] = fmaf(b[t] - mu, a, be[t]);
    }
}

extern "C" void kernel_launch(void* const* d_in, const int* in_sizes, int n_in,
                              void* d_out, int out_size, void* d_ws, size_t ws_size,
                              hipStream_t stream) {
    const int N = NNODES, E = NEDGES;

    const float* x   = (const float*)d_in[0];
    const int* ei    = (const int*)d_in[1];
    const float* W1  = (const float*)d_in[2];
    const float* b1  = (const float*)d_in[3];
    const float* g1  = (const float*)d_in[4];
    const float* be1 = (const float*)d_in[5];
    const float* W2  = (const float*)d_in[6];
    const float* b2  = (const float*)d_in[7];
    const float* g2  = (const float*)d_in[8];
    const float* be2 = (const float*)d_in[9];
    const float* Wmu = (const float*)d_in[10];
    const float* bmu = (const float*)d_in[11];
    const float* Wlv = (const float*)d_in[12];
    const float* blv = (const float*)d_in[13];
    float* out = (float*)d_out;

    const int* src = ei;
    const int* dst = ei + E;

    char* ws = (char*)d_ws;
    size_t off = 0;
    auto alloc = [&](size_t bytes) { char* p = ws + off; off += (bytes + 255) & ~(size_t)255; return p; };
    float*          dinv   = (float*)alloc((size_t)N * 4);
    unsigned short* bufU   = (unsigned short*)alloc((size_t)N * 64 * 2);
    unsigned short* bufS   = (unsigned short*)alloc((size_t)N * 64 * 2);
    int*            degi   = (int*)alloc((size_t)N * 4);
    int*            rowptr = (int*)alloc((size_t)(N + 1) * 4);
    int*            adj    = (int*)alloc((size_t)E * 4);
    unsigned int*   gbuf   = (unsigned int*)alloc((size_t)KBUCK * BCAP * 4);
    int*            gcount = (int*)alloc((size_t)KBUCK * 4);
    int*            partials = (int*)alloc(128 * 4);
    float*          pblk   = (float*)alloc((size_t)NBAGG * 128 * 4);
    float*          pblk2  = (float*)alloc((size_t)NRED * 128 * 4);
    unsigned short* Wt1    = (unsigned short*)alloc(64 * 128 * 2);
    unsigned short* Wt2    = (unsigned short*)alloc(64 * 64 * 2);
    unsigned short* Wtc    = (unsigned short*)alloc(64 * 64 * 2);
    float*          alpha  = (float*)alloc(64 * 4);
    float*          delta  = (float*)alloc(64 * 4);
    (void)ws_size;

    const int B = 256;
    dim3 blk(B);
    int gGemm  = (N + 63) / 64;           // 1563
    int gScan  = (N + 1023) / 1024;       // 98
    int gBin   = (E + CHUNK - 1) / CHUNK; // 391
    const uint2* u2 = (const uint2*)bufU;

    // ---- build CSR: bin -> hist/dinv -> scan -> local fill ----
    hipMemsetAsync(gcount, 0, (size_t)KBUCK * 4, stream);
    k_bin<<<gBin, blk, 0, stream>>>(src, dst, gbuf, gcount, E);
    k_hist_dinv<<<KBUCK, blk, 0, stream>>>(gbuf, gcount, degi, dinv, N);
    k_block_reduce<<<gScan, blk, 0, stream>>>(degi, partials, N);
    k_scan_partials<<<1, 64, 0, stream>>>(partials, gScan);
    k_block_scan<<<gScan, blk, 0, stream>>>(degi, partials, rowptr, N, E);
    k_fill_local<<<KBUCK, blk, 0, stream>>>(gbuf, gcount, rowptr, adj, N);
    k_prep_w<<<32, blk, 0, stream>>>(W1, W2, Wmu, Wlv, Wt1, Wt2, Wtc);

    // ---- layer 1 ----
    k_gemm_mfma<128, false><<<gGemm, blk, 0, stream>>>(x, Wt1, dinv, nullptr, nullptr, bufU, N);
    k_agg4<0><<<NBAGG, blk, 0, stream>>>(rowptr, adj, u2, dinv, b1, nullptr, nullptr,
                                         bufS, nullptr, pblk, N);
    k_reduce_pblk<<<NRED, blk, 0, stream>>>(pblk, pblk2, NBAGG);
    k_bn_finalize2<<<1, blk, 0, stream>>>(pblk2, NRED, g1, be1, b1, alpha, delta, N);

    // ---- layer 2 ----
    k_gemm_mfma<64, true><<<gGemm, blk, 0, stream>>>(bufS, Wt2, dinv, alpha, delta, bufU, N);
    k_agg4<0><<<NBAGG, blk, 0, stream>>>(rowptr, adj, u2, dinv, b2, nullptr, nullptr,
                                         bufS, nullptr, pblk, N);
    k_reduce_pblk<<<NRED, blk, 0, stream>>>(pblk, pblk2, NBAGG);
    k_bn_finalize2<<<1, blk, 0, stream>>>(pblk2, NRED, g2, be2, b2, alpha, delta, N);

    // ---- heads (mu ‖ logvar fused) + final epilogue ----
    k_gemm_mfma<64, true><<<gGemm, blk, 0, stream>>>(bufS, Wtc, dinv, alpha, delta, bufU, N);
    k_agg4<1><<<NBAGG, blk, 0, stream>>>(rowptr, adj, u2, dinv, nullptr, bmu, blv,
                                         nullptr, out, nullptr, N);
}